// Round 6
// baseline (132.712 us; speedup 1.0000x reference)
//
#include <hip/hip_runtime.h>

#define NBINS 10
#define BLOCK 256
#define GRID  2048
#define NWAVE (BLOCK / 64)

// Cumulative form: U[0] = sum of ALL bce, U[j] (j>=1) = sum of bce where xp >= TAU[j-1]
//                  C[j] (j>=1) = count where xp >= TAU[j-1]; C[0] = total (= n, known)
// Per-bin: S_b = U[b] - U[b+1], c_b = C[b] - C[b+1]  (with [10] == 0)
// ws layout: double gU[10] ; unsigned gC[10]

__global__ void ghm_init(double* gU, unsigned* gC) {
    int t = threadIdx.x;
    if (t < NBINS) { gU[t] = 0.0; gC[t] = 0u; }
}

__global__ __launch_bounds__(BLOCK, 6) void ghm_main(const float4* __restrict__ pred,
                                                     const float4* __restrict__ targ,
                                                     int n4,
                                                     double* __restrict__ gU,
                                                     unsigned* __restrict__ gC) {
    // TAU[j] = logit((j+1)/10): bin(x') >= j+1  <=>  x' >= TAU[j]
    const float TAU[9] = {-2.19722458f, -1.38629436f, -0.84729786f, -0.40546511f, 0.0f,
                           0.40546511f,  0.84729786f,  1.38629436f,  2.19722458f};

    float U0 = 0.0f;
    float    Uc[9];
    unsigned Cc[9];
#pragma unroll
    for (int j = 0; j < 9; ++j) { Uc[j] = 0.0f; Cc[j] = 0u; }

    const int stride = GRID * BLOCK;          // == total threads
    const int i = blockIdx.x * BLOCK + threadIdx.x;

    // x' = x*(1-2t) (exact for t in {0,1}):
    //   |sigmoid(x)-t| = sigmoid(x'),  bce = softplus(x') = max(x',0)+ln2*log2(1+2^(-|x'|*log2e))
#define ELEM(px, tx)                                                          \
        {                                                                     \
            float x  = (px);                                                  \
            float xp = x * fmaf(-2.0f, (tx), 1.0f);                           \
            float y  = fabsf(xp) * -1.44269504f;                              \
            float e2 = __builtin_amdgcn_exp2f(y);        /* e^{-|x'|} */      \
            float l2 = __builtin_amdgcn_logf(1.0f + e2); /* log2(1+e) */      \
            float bce = fmaf(0.69314718f, l2, fmaxf(xp, 0.0f));               \
            U0 += bce;                                                        \
            _Pragma("unroll")                                                 \
            for (int j = 0; j < 9; ++j) {                                     \
                bool pg = (xp >= TAU[j]);                                     \
                Uc[j] += pg ? bce : 0.0f;   /* cmp + cndmask + add */         \
                Cc[j] += pg ? 1u : 0u;      /* addc (vcc reuse) */            \
            }                                                                 \
        }
#define QUAD(a, b) ELEM((a).x, (b).x) ELEM((a).y, (b).y) ELEM((a).z, (b).z) ELEM((a).w, (b).w)

    // quads this thread owns (all threads have i < stride <= n4 here)
    const int nq = (i < n4) ? ((n4 - 1 - i) / stride + 1) : 0;

    if (nq >= 2) {
        const float4* pp = pred + i;
        const float4* tp = targ + i;
        // prologue: current pair in registers
        float4 a0 = pp[0], b0 = tp[0];
        float4 a1 = pp[stride], b1 = tp[stride];
        const int npair = nq >> 1;
        for (int k = 1; k < npair; ++k) {
            pp += 2 * stride;
            tp += 2 * stride;
            // issue next pair's 4 loads BEFORE consuming current pair
            float4 c0 = pp[0], d0 = tp[0];
            float4 c1 = pp[stride], d1 = tp[stride];
            QUAD(a0, b0)
            QUAD(a1, b1)
            a0 = c0; b0 = d0; a1 = c1; b1 = d1;
        }
        QUAD(a0, b0)
        QUAD(a1, b1)
        if (nq & 1) {
            pp += 2 * stride;
            tp += 2 * stride;
            float4 a = pp[0], b = tp[0];
            QUAD(a, b)
        }
    } else if (nq == 1) {
        float4 a = pred[i], b = targ[i];
        QUAD(a, b)
    }
#undef QUAD
#undef ELEM

    // Wave butterfly reduction.
#pragma unroll
    for (int m = 1; m < 64; m <<= 1) U0 += __shfl_xor(U0, m, 64);
#pragma unroll
    for (int j = 0; j < 9; ++j) {
#pragma unroll
        for (int m = 1; m < 64; m <<= 1) {
            Uc[j] += __shfl_xor(Uc[j], m, 64);
            Cc[j] += __shfl_xor(Cc[j], m, 64);
        }
    }

    __shared__ float    sU[NWAVE][NBINS];
    __shared__ unsigned sC[NWAVE][NBINS];
    const int wid  = threadIdx.x >> 6;
    const int lane = threadIdx.x & 63;
    if (lane == 0) {
        sU[wid][0] = U0;
        sC[wid][0] = 0u;
#pragma unroll
        for (int j = 0; j < 9; ++j) { sU[wid][1 + j] = Uc[j]; sC[wid][1 + j] = Cc[j]; }
    }
    __syncthreads();

    if (threadIdx.x < NBINS) {
        float    s = 0.0f;
        unsigned c = 0u;
#pragma unroll
        for (int w = 0; w < NWAVE; ++w) {
            s += sU[w][threadIdx.x];
            c += sC[w][threadIdx.x];
        }
        atomicAdd(&gU[threadIdx.x], (double)s);
        if (threadIdx.x > 0) atomicAdd(&gC[threadIdx.x], c);
    }
}

__global__ void ghm_finalize(const double* __restrict__ gU,
                             const unsigned* __restrict__ gC,
                             float* __restrict__ out, unsigned ntot) {
    if (threadIdx.x == 0 && blockIdx.x == 0) {
        double acc = 0.0;
        int n = 0;
        for (int b = 0; b < NBINS; ++b) {
            double   hiU = (b < 9) ? gU[b + 1] : 0.0;
            unsigned hiC = (b < 9) ? gC[b + 1] : 0u;
            double   S = gU[b] - hiU;
            unsigned c = ((b == 0) ? ntot : gC[b]) - hiC;
            if (c > 0u) {
                ++n;
                acc += S / (double)c;
            }
        }
        if (n < 1) n = 1;
        out[0] = (float)(acc / (double)n);
    }
}

extern "C" void kernel_launch(void* const* d_in, const int* in_sizes, int n_in,
                              void* d_out, int out_size, void* d_ws, size_t ws_size,
                              hipStream_t stream) {
    const float4* pred = (const float4*)d_in[0];
    const float4* targ = (const float4*)d_in[1];
    double*   gU = (double*)d_ws;
    unsigned* gC = (unsigned*)((char*)d_ws + NBINS * sizeof(double));
    float* out = (float*)d_out;

    int n4 = in_sizes[0] / 4;
    unsigned ntot = (unsigned)in_sizes[0];

    ghm_init<<<1, 64, 0, stream>>>(gU, gC);
    ghm_main<<<GRID, BLOCK, 0, stream>>>(pred, targ, n4, gU, gC);
    ghm_finalize<<<1, 64, 0, stream>>>(gU, gC, out, ntot);
}

// Round 7
// 119.036 us; speedup vs baseline: 1.1149x; 1.1149x over previous
//
#include <hip/hip_runtime.h>

#define NBINS 10
#define BLOCK 256
#define GRID  1024
#define NWAVE (BLOCK / 64)

// Cumulative form: U[0] = sum of ALL bce, U[j] (j>=1) = sum of bce where xp >= TAU[j-1]
//                  C[j] (j>=1) = count where xp >= TAU[j-1]; C[0] = total (= n, known)
// Per-bin: S_b = U[b] - U[b+1], c_b = C[b] - C[b+1]  (with [10] == 0)
// ws layout: double gU[10] ; unsigned gC[10]

__global__ void ghm_init(double* gU, unsigned* gC) {
    int t = threadIdx.x;
    if (t < NBINS) { gU[t] = 0.0; gC[t] = 0u; }
}

__global__ __launch_bounds__(BLOCK, 4) void ghm_main(const float4* __restrict__ pred,
                                                     const float4* __restrict__ targ,
                                                     int n4,
                                                     double* __restrict__ gU,
                                                     unsigned* __restrict__ gC) {
    float U0 = 0.0f;
    float    Uc[9];
    unsigned Cc[9];
#pragma unroll
    for (int j = 0; j < 9; ++j) { Uc[j] = 0.0f; Cc[j] = 0u; }

    const int stride = GRID * BLOCK;
    const int i = blockIdx.x * BLOCK + threadIdx.x;

    // x' = x*(1-2t) (exact for t in {0,1}):
    //   |sigmoid(x)-t| = sigmoid(x'),  bce = softplus(x') = max(x',0)+ln2*log2(1+2^(-|x'|*log2e))
    // Threshold chain in asm: per threshold exactly 4 VALU ops, vcc reused by addc.
#define THR(T, U, C, VT)                                                      \
        "v_cmp_le_f32 vcc, " T ", %[xp]\n\t"                                  \
        "v_cndmask_b32 " VT ", 0, %[bce], vcc\n\t"                            \
        "v_addc_co_u32 " C ", vcc, 0, " C ", vcc\n\t"                         \
        "v_add_f32 " U ", " U ", " VT "\n\t"

#define ELEM(px, tx)                                                          \
        {                                                                     \
            float x  = (px);                                                  \
            float xp = x * fmaf(-2.0f, (tx), 1.0f);                           \
            float y  = fabsf(xp) * -1.44269504f;                              \
            float e2 = __builtin_amdgcn_exp2f(y);        /* e^{-|x'|} */      \
            float l2 = __builtin_amdgcn_logf(1.0f + e2); /* log2(1+e) */      \
            float bce = fmaf(0.69314718f, l2, fmaxf(xp, 0.0f));               \
            U0 += bce;                                                        \
            float vt0, vt1;                                                   \
            asm volatile(                                                     \
                THR("%[t0]", "%[u0]", "%[c0]", "%[w0]")                       \
                THR("%[t1]", "%[u1]", "%[c1]", "%[w1]")                       \
                THR("%[t2]", "%[u2]", "%[c2]", "%[w0]")                       \
                THR("%[t3]", "%[u3]", "%[c3]", "%[w1]")                       \
                THR("%[t4]", "%[u4]", "%[c4]", "%[w0]")                       \
                : [u0]"+v"(Uc[0]), [c0]"+v"(Cc[0]),                           \
                  [u1]"+v"(Uc[1]), [c1]"+v"(Cc[1]),                           \
                  [u2]"+v"(Uc[2]), [c2]"+v"(Cc[2]),                           \
                  [u3]"+v"(Uc[3]), [c3]"+v"(Cc[3]),                           \
                  [u4]"+v"(Uc[4]), [c4]"+v"(Cc[4]),                           \
                  [w0]"=&v"(vt0), [w1]"=&v"(vt1)                              \
                : [xp]"v"(xp), [bce]"v"(bce),                                 \
                  [t0]"s"(-2.19722458f), [t1]"s"(-1.38629436f),               \
                  [t2]"s"(-0.84729786f), [t3]"s"(-0.40546511f),               \
                  [t4]"s"(0.0f)                                               \
                : "vcc");                                                     \
            asm volatile(                                                     \
                THR("%[t5]", "%[u5]", "%[c5]", "%[w0]")                       \
                THR("%[t6]", "%[u6]", "%[c6]", "%[w1]")                       \
                THR("%[t7]", "%[u7]", "%[c7]", "%[w0]")                       \
                THR("%[t8]", "%[u8]", "%[c8]", "%[w1]")                       \
                : [u5]"+v"(Uc[5]), [c5]"+v"(Cc[5]),                           \
                  [u6]"+v"(Uc[6]), [c6]"+v"(Cc[6]),                           \
                  [u7]"+v"(Uc[7]), [c7]"+v"(Cc[7]),                           \
                  [u8]"+v"(Uc[8]), [c8]"+v"(Cc[8]),                           \
                  [w0]"=&v"(vt0), [w1]"=&v"(vt1)                              \
                : [xp]"v"(xp), [bce]"v"(bce),                                 \
                  [t5]"s"(0.40546511f), [t6]"s"(0.84729786f),                 \
                  [t7]"s"(1.38629436f), [t8]"s"(2.19722458f)                  \
                : "vcc");                                                     \
        }
#define QUAD(a, b) ELEM((a).x, (b).x) ELEM((a).y, (b).y) ELEM((a).z, (b).z) ELEM((a).w, (b).w)

    const int nq = (i < n4) ? ((n4 - 1 - i) / stride + 1) : 0;

    if (nq >= 2) {
        const float4* pp = pred + i;
        const float4* tp = targ + i;
        float4 a0 = pp[0], b0 = tp[0];
        float4 a1 = pp[stride], b1 = tp[stride];
        const int npair = nq >> 1;
        for (int k = 1; k < npair; ++k) {
            pp += 2 * stride;
            tp += 2 * stride;
            // next pair's 4 loads issued before consuming current pair
            float4 c0 = pp[0], d0 = tp[0];
            float4 c1 = pp[stride], d1 = tp[stride];
            QUAD(a0, b0)
            QUAD(a1, b1)
            a0 = c0; b0 = d0; a1 = c1; b1 = d1;
        }
        QUAD(a0, b0)
        QUAD(a1, b1)
        if (nq & 1) {
            pp += 2 * stride;
            tp += 2 * stride;
            float4 a = pp[0], b = tp[0];
            QUAD(a, b)
        }
    } else if (nq == 1) {
        float4 a = pred[i], b = targ[i];
        QUAD(a, b)
    }
#undef QUAD
#undef ELEM
#undef THR

    // Wave butterfly reduction.
#pragma unroll
    for (int m = 1; m < 64; m <<= 1) U0 += __shfl_xor(U0, m, 64);
#pragma unroll
    for (int j = 0; j < 9; ++j) {
#pragma unroll
        for (int m = 1; m < 64; m <<= 1) {
            Uc[j] += __shfl_xor(Uc[j], m, 64);
            Cc[j] += __shfl_xor(Cc[j], m, 64);
        }
    }

    __shared__ float    sU[NWAVE][NBINS];
    __shared__ unsigned sC[NWAVE][NBINS];
    const int wid  = threadIdx.x >> 6;
    const int lane = threadIdx.x & 63;
    if (lane == 0) {
        sU[wid][0] = U0;
        sC[wid][0] = 0u;
#pragma unroll
        for (int j = 0; j < 9; ++j) { sU[wid][1 + j] = Uc[j]; sC[wid][1 + j] = Cc[j]; }
    }
    __syncthreads();

    if (threadIdx.x < NBINS) {
        float    s = 0.0f;
        unsigned c = 0u;
#pragma unroll
        for (int w = 0; w < NWAVE; ++w) {
            s += sU[w][threadIdx.x];
            c += sC[w][threadIdx.x];
        }
        atomicAdd(&gU[threadIdx.x], (double)s);
        if (threadIdx.x > 0) atomicAdd(&gC[threadIdx.x], c);
    }
}

__global__ void ghm_finalize(const double* __restrict__ gU,
                             const unsigned* __restrict__ gC,
                             float* __restrict__ out, unsigned ntot) {
    if (threadIdx.x == 0 && blockIdx.x == 0) {
        double acc = 0.0;
        int n = 0;
        for (int b = 0; b < NBINS; ++b) {
            double   hiU = (b < 9) ? gU[b + 1] : 0.0;
            unsigned hiC = (b < 9) ? gC[b + 1] : 0u;
            double   S = gU[b] - hiU;
            unsigned c = ((b == 0) ? ntot : gC[b]) - hiC;
            if (c > 0u) {
                ++n;
                acc += S / (double)c;
            }
        }
        if (n < 1) n = 1;
        out[0] = (float)(acc / (double)n);
    }
}

extern "C" void kernel_launch(void* const* d_in, const int* in_sizes, int n_in,
                              void* d_out, int out_size, void* d_ws, size_t ws_size,
                              hipStream_t stream) {
    const float4* pred = (const float4*)d_in[0];
    const float4* targ = (const float4*)d_in[1];
    double*   gU = (double*)d_ws;
    unsigned* gC = (unsigned*)((char*)d_ws + NBINS * sizeof(double));
    float* out = (float*)d_out;

    int n4 = in_sizes[0] / 4;
    unsigned ntot = (unsigned)in_sizes[0];

    ghm_init<<<1, 64, 0, stream>>>(gU, gC);
    ghm_main<<<GRID, BLOCK, 0, stream>>>(pred, targ, n4, gU, gC);
    ghm_finalize<<<1, 64, 0, stream>>>(gU, gC, out, ntot);
}